// Round 7
// baseline (605.608 us; speedup 1.0000x reference)
//
#include <hip/hip_runtime.h>

#define B_N 4096
#define F_N 1024
#define H_N 4
#define D_N 256
#define BF_ELEMS (B_N * F_N)   // 4194304
#define REPS 4                 // diagnostic: x4 repeat so each kernel clears the
                               // ~88us harness-fill bar and shows in rocprof top-5.
                               // Identical work each rep -> deterministic, correct.

typedef unsigned short u16;
typedef __bf16 bf16x8 __attribute__((ext_vector_type(8)));
typedef float f32x4 __attribute__((ext_vector_type(4)));
typedef u16 u16x4 __attribute__((ext_vector_type(4)));

__device__ __forceinline__ u16 f2bf(float v) {
    union { float f; unsigned u; } x; x.f = v;
    unsigned r = x.u + 0x7fffu + ((x.u >> 16) & 1u);
    return (u16)(r >> 16);
}

__device__ __forceinline__ float bf2f(u16 v) {
    union { unsigned u; float f; } x; x.u = ((unsigned)v) << 16;
    return x.f;
}

// Fused prep: blocks 0..4095 = conv step + state shift + flag + bf16 casts;
// blocks 4096..6143 = weight f32->bf16 transpose [k][e] -> [e][k].
__global__ __launch_bounds__(256) void kprep(
    const float* __restrict__ inputs, const float* __restrict__ cs,
    const float* __restrict__ ck, const float* __restrict__ cb,
    const float* __restrict__ h, const float* __restrict__ n,
    const float* W0, const float* W1, const float* W2, const float* W3,
    const float* W4, const float* W5, const float* W6, const float* W7,
    float* __restrict__ ncs_out, u16* __restrict__ convact,
    u16* __restrict__ hbf, u16* __restrict__ inbf,
    u16* __restrict__ wt, int* __restrict__ flag) {
    __shared__ float tile[32][33];
    int bid = blockIdx.x;
    int t = threadIdx.x;
    for (int rep = 0; rep < REPS; ++rep) {
    if (bid < 4096) {
        int idx = bid * 256 + t;
        int flat = idx << 2;
        int b = flat >> 10;
        int f = flat & 1023;
        const f32x4 x  = *(const f32x4*)(inputs + flat);
        const f32x4 c1 = *(const f32x4*)(cs + b * 4096 + 1024 + f);
        const f32x4 c2 = *(const f32x4*)(cs + b * 4096 + 2048 + f);
        const f32x4 c3 = *(const f32x4*)(cs + b * 4096 + 3072 + f);
        const f32x4 k0 = *(const f32x4*)(ck + f);
        const f32x4 k1 = *(const f32x4*)(ck + 1024 + f);
        const f32x4 k2 = *(const f32x4*)(ck + 2048 + f);
        const f32x4 k3 = *(const f32x4*)(ck + 3072 + f);
        const f32x4 bias = *(const f32x4*)(cb + f);
        const f32x4 h4 = *(const f32x4*)(h + flat);
        const f32x4 nv = *(const f32x4*)(n + flat);

        bool any = (nv[0] != 0.f) || (nv[1] != 0.f) || (nv[2] != 0.f) || (nv[3] != 0.f);
        unsigned long long msk = __ballot(any);
        if (msk && (t & 63) == 0) *flag = 1;

        u16x4 ca, hb, ib;
        #pragma unroll
        for (int q = 0; q < 4; ++q) {
            float v = c1[q] * k0[q] + c2[q] * k1[q] + c3[q] * k2[q] + x[q] * k3[q] + bias[q];
            float a = v / (1.f + expf(-v));   // silu
            ca[q] = f2bf(a);
            hb[q] = f2bf(h4[q]);
            ib[q] = f2bf(x[q]);
        }
        *(u16x4*)(convact + flat) = ca;
        *(u16x4*)(hbf + flat) = hb;
        *(u16x4*)(inbf + flat) = ib;

        float* ob = ncs_out + b * 4096 + f;
        *(f32x4*)(ob)        = c1;
        *(f32x4*)(ob + 1024) = c2;
        *(f32x4*)(ob + 2048) = c3;
        *(f32x4*)(ob + 3072) = x;
    } else {
        int wb = bid - 4096;          // 0..2047 = 64 tiles x 4 heads x 8 mats
        int gx = wb & 63;
        int hd = (wb >> 6) & 3;
        int mat = wb >> 8;
        const float* tab[8] = {W0, W1, W2, W3, W4, W5, W6, W7};
        const float* src = tab[mat] + hd * 65536;
        u16* dst = wt + (mat * 4 + hd) * 65536;
        int tx = t & 31, ty = t >> 5;
        int bx = (gx & 7) * 32;   // e tile
        int by = (gx >> 3) * 32;  // k tile
        #pragma unroll
        for (int r = 0; r < 4; ++r)
            tile[ty + r * 8][tx] = src[(by + ty + r * 8) * 256 + bx + tx];
        __syncthreads();
        #pragma unroll
        for (int r = 0; r < 4; ++r)
            dst[(bx + ty + r * 8) * 256 + by + tx] = f2bf(tile[tx][ty + r * 8]);
        __syncthreads();   // rep boundary: tile reuse
    }
    }
}

// gates16[g][b][hd*256+e] = bf16( x_g . W_g + h . R_g + b_g )
// 256x256 tile per block, BK=64, prefetch dbuf, XOR-swizzled LDS staging.
// grid: x = 16 (M/256), y = 16 (gsel*4 + head); 256 blocks = 1/CU.
__global__ __launch_bounds__(512, 2) void kgemm(
    const u16* __restrict__ convact, const u16* __restrict__ inbf,
    const u16* __restrict__ hbf, const u16* __restrict__ wt,
    const float* __restrict__ bgi, const float* __restrict__ bgf,
    const float* __restrict__ bgz, const float* __restrict__ bgo,
    u16* __restrict__ gates16) {
    __shared__ u16 ldsA[2][256 * 64];   // 64 KB
    __shared__ u16 ldsB[2][256 * 64];   // 64 KB

    int t = threadIdx.x;
    int mtile = blockIdx.x;
    int pairidx = blockIdx.y;
    int gsel = pairidx >> 2;          // 0=i,1=f,2=z,3=o
    int hd = pairidx & 3;
    int row0 = mtile * 256;

    const u16* a0 = (gsel >= 2 ? inbf : convact) + row0 * 1024 + hd * 256;
    const u16* a1 = hbf + row0 * 1024 + hd * 256;
    const u16* b0 = wt + (gsel * 4 + hd) * 65536;         // W part [e][256k]
    const u16* b1 = wt + ((gsel + 4) * 4 + hd) * 65536;   // R part
    const float* bias = (gsel == 0 ? bgi : gsel == 1 ? bgf : gsel == 2 ? bgz : bgo) + hd * 256;

    int lane = t & 63;
    int lr = lane & 15, lk = lane >> 4;
    int w = t >> 6;
    int wm = w >> 2, wn = w & 3;
    int wbase = t & ~63;                       // wave-uniform granule base
    int srow = t >> 3;                         // staging row (0..63), +s*64
    int gsw = (t & 7) ^ ((t >> 3) & 7);        // swizzled source granule

    #define STAGE_TILE(buf, kt) do {                                              \
        int kb = (kt) * 64;                                                       \
        const u16* ap = (kb < 256) ? (a0 + kb) : (a1 + (kb - 256));               \
        const u16* bp = (kb < 256) ? (b0 + kb) : (b1 + (kb - 256));               \
        _Pragma("unroll")                                                         \
        for (int s = 0; s < 4; ++s) {                                             \
            int row = srow + s * 64;                                              \
            __builtin_amdgcn_global_load_lds(                                     \
                (const __attribute__((address_space(1))) void*)(ap + row * 1024 + gsw * 8), \
                (__attribute__((address_space(3))) void*)(&ldsA[buf][(s * 512 + wbase) * 8]), \
                16, 0, 0);                                                        \
        }                                                                         \
        _Pragma("unroll")                                                         \
        for (int s = 0; s < 4; ++s) {                                             \
            int row = srow + s * 64;                                              \
            __builtin_amdgcn_global_load_lds(                                     \
                (const __attribute__((address_space(1))) void*)(bp + row * 256 + gsw * 8), \
                (__attribute__((address_space(3))) void*)(&ldsB[buf][(s * 512 + wbase) * 8]), \
                16, 0, 0);                                                        \
        }                                                                         \
    } while (0)

    for (int rep = 0; rep < REPS; ++rep) {
    f32x4 acc[8][4];
    #pragma unroll
    for (int i = 0; i < 8; ++i)
        #pragma unroll
        for (int j = 0; j < 4; ++j)
            acc[i][j] = (f32x4){0.f, 0.f, 0.f, 0.f};

    STAGE_TILE(0, 0);
    __syncthreads();

    for (int kt = 0; kt < 8; ++kt) {
        int buf = kt & 1;
        if (kt < 7) STAGE_TILE(buf ^ 1, kt + 1);

        #pragma unroll
        for (int kk = 0; kk < 2; ++kk) {
            bf16x8 a[8], bb[4];
            #pragma unroll
            for (int mi = 0; mi < 8; ++mi) {
                int row = wm * 128 + mi * 16 + lr;
                a[mi] = *(const bf16x8*)&ldsA[buf][row * 64 + (((kk * 4 + lk) ^ (lr & 7)) * 8)];
            }
            #pragma unroll
            for (int ni = 0; ni < 4; ++ni) {
                int row = wn * 64 + ni * 16 + lr;
                bb[ni] = *(const bf16x8*)&ldsB[buf][row * 64 + (((kk * 4 + lk) ^ (lr & 7)) * 8)];
            }
            #pragma unroll
            for (int mi = 0; mi < 8; ++mi)
                #pragma unroll
                for (int ni = 0; ni < 4; ++ni)
                    acc[mi][ni] = __builtin_amdgcn_mfma_f32_16x16x32_bf16(a[mi], bb[ni], acc[mi][ni], 0, 0, 0);
        }
        __syncthreads();   // drains vmcnt(0): this iter's prefetch has landed
    }

    float bv[4];
    #pragma unroll
    for (int ni = 0; ni < 4; ++ni)
        bv[ni] = bias[wn * 64 + ni * 16 + lr];

    u16* gout = gates16 + (size_t)gsel * BF_ELEMS;
    #pragma unroll
    for (int mi = 0; mi < 8; ++mi)
        #pragma unroll
        for (int ni = 0; ni < 4; ++ni)
            #pragma unroll
            for (int r = 0; r < 4; ++r) {
                int row = row0 + wm * 128 + mi * 16 + lk * 4 + r;
                int col = hd * 256 + wn * 64 + ni * 16 + lr;
                gout[row * 1024 + col] = f2bf(acc[mi][ni][r] + bv[ni]);
            }
    }
    #undef STAGE_TILE
}

// pointwise gate math + per-head LayerNorm; one block per row, one wave per head
__global__ __launch_bounds__(256) void kpoint(
    const u16* __restrict__ gates16,
    const float* __restrict__ c, const float* __restrict__ n, const float* __restrict__ m,
    const float* __restrict__ ln_scale, const int* __restrict__ flagp,
    float* __restrict__ out) {
    int b = blockIdx.x;
    int t = threadIdx.x;
    int l = t & 63;
    int j = (t >> 6) * 256 + l * 4;
    int idx = b * 1024 + j;
    for (int rep = 0; rep < REPS; ++rep) {
    int flag = *flagp;

    u16x4 iv = *(const u16x4*)(gates16 + idx);
    u16x4 fv = *(const u16x4*)(gates16 + (size_t)BF_ELEMS + idx);
    u16x4 zv = *(const u16x4*)(gates16 + 2 * (size_t)BF_ELEMS + idx);
    u16x4 ov = *(const u16x4*)(gates16 + 3 * (size_t)BF_ELEMS + idx);
    f32x4 cv = *(const f32x4*)(c + idx);
    f32x4 nv = *(const f32x4*)(n + idx);
    f32x4 mv = *(const f32x4*)(m + idx);
    f32x4 sc = *(const f32x4*)(ln_scale + j);

    f32x4 cn, nn, mn, hn;
    float s = 0.f, ss = 0.f;
    #pragma unroll
    for (int q = 0; q < 4; ++q) {
        float I = bf2f(iv[q]);
        float Fg = bf2f(fv[q]);
        float Z = bf2f(zv[q]);
        float O = bf2f(ov[q]);
        float og = 1.f / (1.f + expf(-O));
        float lf = (Fg >= 0.f) ? -log1pf(expf(-Fg)) : (Fg - log1pf(expf(Fg)));
        float mnew = flag ? fmaxf(lf + mv[q], I) : I;
        float ip = fminf(expf(I - mnew), 1.f);
        float fp = fminf(expf(lf + mv[q] - mnew), 1.f);
        float cnew = fp * cv[q] + ip * tanhf(Z);
        float nnew = fp * nv[q] + ip;
        float hnew = og * (cnew / fmaxf(nnew, 1e-6f));
        cn[q] = cnew; nn[q] = nnew; mn[q] = mnew; hn[q] = hnew;
        s += hnew; ss += hnew * hnew;
    }
    #pragma unroll
    for (int off = 32; off >= 1; off >>= 1) {
        s  += __shfl_xor(s, off);
        ss += __shfl_xor(ss, off);
    }
    float mu = s * (1.f / 256.f);
    float var = ss * (1.f / 256.f) - mu * mu;
    float rs = rsqrtf(var + 1e-6f);

    f32x4 o4;
    #pragma unroll
    for (int q = 0; q < 4; ++q)
        o4[q] = (hn[q] - mu) * rs * sc[q];

    *(f32x4*)(out + idx) = o4;
    *(f32x4*)(out + (size_t)BF_ELEMS + idx) = cn;
    *(f32x4*)(out + 2 * (size_t)BF_ELEMS + idx) = nn;
    *(f32x4*)(out + 3 * (size_t)BF_ELEMS + idx) = mn;
    *(f32x4*)(out + 4 * (size_t)BF_ELEMS + idx) = hn;
    }
}

extern "C" void kernel_launch(void* const* d_in, const int* in_sizes, int n_in,
                              void* d_out, int out_size, void* d_ws, size_t ws_size,
                              hipStream_t stream) {
    const float* inputs = (const float*)d_in[0];
    const float* c = (const float*)d_in[1];
    const float* n = (const float*)d_in[2];
    const float* m = (const float*)d_in[3];
    const float* h = (const float*)d_in[4];
    const float* conv_state = (const float*)d_in[5];
    const float* conv_kernel = (const float*)d_in[6];
    const float* conv_bias = (const float*)d_in[7];
    const float* W[8];
    for (int i = 0; i < 8; ++i) W[i] = (const float*)d_in[8 + i];
    const float* bgi = (const float*)d_in[16];
    const float* bgf = (const float*)d_in[17];
    const float* bgz = (const float*)d_in[18];
    const float* bgo = (const float*)d_in[19];
    const float* ln_scale = (const float*)d_in[20];
    float* out = (float*)d_out;

    char* ws = (char*)d_ws;
    int* flag = (int*)ws;
    u16* convact = (u16*)(ws + 256);
    u16* hbf = convact + BF_ELEMS;
    u16* inbf = hbf + BF_ELEMS;
    u16* wt = inbf + BF_ELEMS;                       // 8*4*65536 bf16
    u16* gates16 = wt + (size_t)8 * 4 * 65536;       // 4 * BF_ELEMS bf16

    hipMemsetAsync(flag, 0, 4, stream);
    kprep<<<6144, 256, 0, stream>>>(inputs, conv_state, conv_kernel, conv_bias, h, n,
                                    W[0], W[1], W[2], W[3], W[4], W[5], W[6], W[7],
                                    out + 5 * (size_t)BF_ELEMS, convact, hbf, inbf, wt, flag);
    kgemm<<<dim3(16, 16), 512, 0, stream>>>(convact, inbf, hbf, wt,
                                            bgi, bgf, bgz, bgo, gates16);
    kpoint<<<4096, 256, 0, stream>>>(gates16, c, n, m, ln_scale, flag, out);
}

// Round 8
// 113.997 us; speedup vs baseline: 5.3125x; 5.3125x over previous
//
#include <hip/hip_runtime.h>

#define B_N 4096
#define F_N 1024
#define H_N 4
#define D_N 256
#define BF_ELEMS (B_N * F_N)   // 4194304

typedef unsigned short u16;
typedef __bf16 bf16x8 __attribute__((ext_vector_type(8)));
typedef float f32x4 __attribute__((ext_vector_type(4)));
typedef u16 u16x4 __attribute__((ext_vector_type(4)));

__device__ __forceinline__ u16 f2bf(float v) {
    union { float f; unsigned u; } x; x.f = v;
    unsigned r = x.u + 0x7fffu + ((x.u >> 16) & 1u);
    return (u16)(r >> 16);
}

__device__ __forceinline__ float bf2f(u16 v) {
    union { unsigned u; float f; } x; x.u = ((unsigned)v) << 16;
    return x.f;
}

// Fused prep: blocks 0..4095 = conv step + state shift + flag + bf16 casts;
// blocks 4096..6143 = weight f32->bf16 transpose [k][e] -> [e][k].
__global__ __launch_bounds__(256) void kprep(
    const float* __restrict__ inputs, const float* __restrict__ cs,
    const float* __restrict__ ck, const float* __restrict__ cb,
    const float* __restrict__ h, const float* __restrict__ n,
    const float* W0, const float* W1, const float* W2, const float* W3,
    const float* W4, const float* W5, const float* W6, const float* W7,
    float* __restrict__ ncs_out, u16* __restrict__ convact,
    u16* __restrict__ hbf, u16* __restrict__ inbf,
    u16* __restrict__ wt, int* __restrict__ flag) {
    __shared__ float tile[32][33];
    int bid = blockIdx.x;
    int t = threadIdx.x;
    if (bid < 4096) {
        int idx = bid * 256 + t;
        int flat = idx << 2;
        int b = flat >> 10;
        int f = flat & 1023;
        const f32x4 x  = *(const f32x4*)(inputs + flat);
        const f32x4 c1 = *(const f32x4*)(cs + b * 4096 + 1024 + f);
        const f32x4 c2 = *(const f32x4*)(cs + b * 4096 + 2048 + f);
        const f32x4 c3 = *(const f32x4*)(cs + b * 4096 + 3072 + f);
        const f32x4 k0 = *(const f32x4*)(ck + f);
        const f32x4 k1 = *(const f32x4*)(ck + 1024 + f);
        const f32x4 k2 = *(const f32x4*)(ck + 2048 + f);
        const f32x4 k3 = *(const f32x4*)(ck + 3072 + f);
        const f32x4 bias = *(const f32x4*)(cb + f);
        const f32x4 h4 = *(const f32x4*)(h + flat);
        const f32x4 nv = *(const f32x4*)(n + flat);

        // any(n != 0): benign race, only 1 ever stored (plain store per wave)
        bool any = (nv[0] != 0.f) || (nv[1] != 0.f) || (nv[2] != 0.f) || (nv[3] != 0.f);
        unsigned long long msk = __ballot(any);
        if (msk && (t & 63) == 0) *flag = 1;

        u16x4 ca, hb, ib;
        #pragma unroll
        for (int q = 0; q < 4; ++q) {
            float v = c1[q] * k0[q] + c2[q] * k1[q] + c3[q] * k2[q] + x[q] * k3[q] + bias[q];
            float a = v / (1.f + expf(-v));   // silu
            ca[q] = f2bf(a);
            hb[q] = f2bf(h4[q]);
            ib[q] = f2bf(x[q]);
        }
        *(u16x4*)(convact + flat) = ca;
        *(u16x4*)(hbf + flat) = hb;
        *(u16x4*)(inbf + flat) = ib;

        float* ob = ncs_out + b * 4096 + f;
        *(f32x4*)(ob)        = c1;
        *(f32x4*)(ob + 1024) = c2;
        *(f32x4*)(ob + 2048) = c3;
        *(f32x4*)(ob + 3072) = x;
    } else {
        int wb = bid - 4096;          // 0..2047 = 64 tiles x 4 heads x 8 mats
        int gx = wb & 63;
        int hd = (wb >> 6) & 3;
        int mat = wb >> 8;
        const float* tab[8] = {W0, W1, W2, W3, W4, W5, W6, W7};
        const float* src = tab[mat] + hd * 65536;
        u16* dst = wt + (mat * 4 + hd) * 65536;
        int tx = t & 31, ty = t >> 5;
        int bx = (gx & 7) * 32;   // e tile
        int by = (gx >> 3) * 32;  // k tile
        #pragma unroll
        for (int r = 0; r < 4; ++r)
            tile[ty + r * 8][tx] = src[(by + ty + r * 8) * 256 + bx + tx];
        __syncthreads();
        #pragma unroll
        for (int r = 0; r < 4; ++r)
            dst[(bx + ty + r * 8) * 256 + by + tx] = f2bf(tile[tx][ty + r * 8]);
    }
}

// gates16[g][b][hd*256+e] = bf16( x_g . W_g + h . R_g + b_g )
// 128x128 tile per block, BK=64, prefetch dbuf, XOR-swizzled staging (verified
// 0 bank conflicts). 256 threads, 4 waves as 2x2, wave tile 64x64, acc 4x4
// f32x4 = 64 VGPR. NO min-occupancy launch_bounds arg: the R5-R7 cap of 128
// VGPR forced accumulator spills (~44 MB/rep scratch writes in the R7 probe).
// LDS 64 KB -> 2 blocks/CU. grid: x = 32 mtiles (fast, shares weights in L2),
// y = 32 coltiles (gsel*8 + etile).
__global__ __launch_bounds__(256) void kgemm(
    const u16* __restrict__ convact, const u16* __restrict__ inbf,
    const u16* __restrict__ hbf, const u16* __restrict__ wt,
    const float* __restrict__ bgi, const float* __restrict__ bgf,
    const float* __restrict__ bgz, const float* __restrict__ bgo,
    u16* __restrict__ gates16) {
    __shared__ u16 ldsA[2][128 * 64];   // 32 KB
    __shared__ u16 ldsB[2][128 * 64];   // 32 KB

    int t = threadIdx.x;
    int mtile = blockIdx.x;
    int ct = blockIdx.y;
    int gsel = ct >> 3;               // 0=i,1=f,2=z,3=o
    int etile = ct & 7;               // 0..7 -> col0 = etile*128 in gate row
    int hd = etile >> 1;
    int e0 = (etile & 1) * 128;       // within head
    int row0 = mtile * 128;

    const u16* a0 = (gsel >= 2 ? inbf : convact) + row0 * 1024 + hd * 256;
    const u16* a1 = hbf + row0 * 1024 + hd * 256;
    const u16* b0 = wt + (gsel * 4 + hd) * 65536 + e0 * 256;         // W part
    const u16* b1 = wt + ((gsel + 4) * 4 + hd) * 65536 + e0 * 256;   // R part
    const float* bias = (gsel == 0 ? bgi : gsel == 1 ? bgf : gsel == 2 ? bgz : bgo)
                        + hd * 256 + e0;

    f32x4 acc[4][4];
    #pragma unroll
    for (int i = 0; i < 4; ++i)
        #pragma unroll
        for (int j = 0; j < 4; ++j)
            acc[i][j] = (f32x4){0.f, 0.f, 0.f, 0.f};

    int lane = t & 63;
    int lr = lane & 15, lk = lane >> 4;
    int w = t >> 6;
    int wm = w >> 1, wn = w & 1;
    int wbase = t & ~63;                       // wave-uniform granule base
    int srow = t >> 3;                         // staging row (0..31), +s*32
    int gsw = (t & 7) ^ ((t >> 3) & 7);        // swizzled source granule

    // Stage K-tile kt into buffer buf. Logical granule (row,g) lands at LDS
    // slot (row, g ^ (row&7)); 4 rounds of 256 granules per 16 KB tile.
    // row&7 invariant under +32*s.
    #define STAGE_TILE(buf, kt) do {                                              \
        int kb = (kt) * 64;                                                       \
        const u16* ap = (kb < 256) ? (a0 + kb) : (a1 + (kb - 256));               \
        const u16* bp = (kb < 256) ? (b0 + kb) : (b1 + (kb - 256));               \
        _Pragma("unroll")                                                         \
        for (int s = 0; s < 4; ++s) {                                             \
            int row = srow + s * 32;                                              \
            __builtin_amdgcn_global_load_lds(                                     \
                (const __attribute__((address_space(1))) void*)(ap + row * 1024 + gsw * 8), \
                (__attribute__((address_space(3))) void*)(&ldsA[buf][(s * 256 + wbase) * 8]), \
                16, 0, 0);                                                        \
        }                                                                         \
        _Pragma("unroll")                                                         \
        for (int s = 0; s < 4; ++s) {                                             \
            int row = srow + s * 32;                                              \
            __builtin_amdgcn_global_load_lds(                                     \
                (const __attribute__((address_space(1))) void*)(bp + row * 256 + gsw * 8), \
                (__attribute__((address_space(3))) void*)(&ldsB[buf][(s * 256 + wbase) * 8]), \
                16, 0, 0);                                                        \
        }                                                                         \
    } while (0)

    STAGE_TILE(0, 0);
    __syncthreads();

    for (int kt = 0; kt < 8; ++kt) {
        int buf = kt & 1;
        if (kt < 7) STAGE_TILE(buf ^ 1, kt + 1);

        #pragma unroll
        for (int kk = 0; kk < 2; ++kk) {
            bf16x8 a[4], bb[4];
            #pragma unroll
            for (int mi = 0; mi < 4; ++mi) {
                int row = wm * 64 + mi * 16 + lr;
                a[mi] = *(const bf16x8*)&ldsA[buf][row * 64 + (((kk * 4 + lk) ^ (row & 7)) * 8)];
            }
            #pragma unroll
            for (int ni = 0; ni < 4; ++ni) {
                int row = wn * 64 + ni * 16 + lr;
                bb[ni] = *(const bf16x8*)&ldsB[buf][row * 64 + (((kk * 4 + lk) ^ (row & 7)) * 8)];
            }
            #pragma unroll
            for (int mi = 0; mi < 4; ++mi)
                #pragma unroll
                for (int ni = 0; ni < 4; ++ni)
                    acc[mi][ni] = __builtin_amdgcn_mfma_f32_16x16x32_bf16(a[mi], bb[ni], acc[mi][ni], 0, 0, 0);
        }
        __syncthreads();   // drains vmcnt(0): this iter's prefetch has landed
    }

    // epilogue: + bias, convert bf16, store
    float bv[4];
    #pragma unroll
    for (int ni = 0; ni < 4; ++ni)
        bv[ni] = bias[wn * 64 + ni * 16 + lr];

    u16* gout = gates16 + (size_t)gsel * BF_ELEMS;
    #pragma unroll
    for (int mi = 0; mi < 4; ++mi)
        #pragma unroll
        for (int ni = 0; ni < 4; ++ni)
            #pragma unroll
            for (int r = 0; r < 4; ++r) {
                int row = row0 + wm * 64 + mi * 16 + lk * 4 + r;
                int col = hd * 256 + e0 + wn * 64 + ni * 16 + lr;
                gout[row * 1024 + col] = f2bf(acc[mi][ni][r] + bv[ni]);
            }
    #undef STAGE_TILE
}

// pointwise gate math + per-head LayerNorm; one block per row, one wave per head
__global__ __launch_bounds__(256) void kpoint(
    const u16* __restrict__ gates16,
    const float* __restrict__ c, const float* __restrict__ n, const float* __restrict__ m,
    const float* __restrict__ ln_scale, const int* __restrict__ flagp,
    float* __restrict__ out) {
    int b = blockIdx.x;
    int t = threadIdx.x;
    int l = t & 63;
    int j = (t >> 6) * 256 + l * 4;
    int idx = b * 1024 + j;
    int flag = *flagp;

    u16x4 iv = *(const u16x4*)(gates16 + idx);
    u16x4 fv = *(const u16x4*)(gates16 + (size_t)BF_ELEMS + idx);
    u16x4 zv = *(const u16x4*)(gates16 + 2 * (size_t)BF_ELEMS + idx);
    u16x4 ov = *(const u16x4*)(gates16 + 3 * (size_t)BF_ELEMS + idx);
    f32x4 cv = *(const f32x4*)(c + idx);
    f32x4 nv = *(const f32x4*)(n + idx);
    f32x4 mv = *(const f32x4*)(m + idx);
    f32x4 sc = *(const f32x4*)(ln_scale + j);

    f32x4 cn, nn, mn, hn;
    float s = 0.f, ss = 0.f;
    #pragma unroll
    for (int q = 0; q < 4; ++q) {
        float I = bf2f(iv[q]);
        float Fg = bf2f(fv[q]);
        float Z = bf2f(zv[q]);
        float O = bf2f(ov[q]);
        float og = 1.f / (1.f + expf(-O));
        float lf = (Fg >= 0.f) ? -log1pf(expf(-Fg)) : (Fg - log1pf(expf(Fg)));
        float mnew = flag ? fmaxf(lf + mv[q], I) : I;
        float ip = fminf(expf(I - mnew), 1.f);
        float fp = fminf(expf(lf + mv[q] - mnew), 1.f);
        float cnew = fp * cv[q] + ip * tanhf(Z);
        float nnew = fp * nv[q] + ip;
        float hnew = og * (cnew / fmaxf(nnew, 1e-6f));
        cn[q] = cnew; nn[q] = nnew; mn[q] = mnew; hn[q] = hnew;
        s += hnew; ss += hnew * hnew;
    }
    #pragma unroll
    for (int off = 32; off >= 1; off >>= 1) {
        s  += __shfl_xor(s, off);
        ss += __shfl_xor(ss, off);
    }
    float mu = s * (1.f / 256.f);
    float var = ss * (1.f / 256.f) - mu * mu;
    float rs = rsqrtf(var + 1e-6f);

    f32x4 o4;
    #pragma unroll
    for (int q = 0; q < 4; ++q)
        o4[q] = (hn[q] - mu) * rs * sc[q];

    *(f32x4*)(out + idx) = o4;
    *(f32x4*)(out + (size_t)BF_ELEMS + idx) = cn;
    *(f32x4*)(out + 2 * (size_t)BF_ELEMS + idx) = nn;
    *(f32x4*)(out + 3 * (size_t)BF_ELEMS + idx) = mn;
    *(f32x4*)(out + 4 * (size_t)BF_ELEMS + idx) = hn;
}

extern "C" void kernel_launch(void* const* d_in, const int* in_sizes, int n_in,
                              void* d_out, int out_size, void* d_ws, size_t ws_size,
                              hipStream_t stream) {
    const float* inputs = (const float*)d_in[0];
    const float* c = (const float*)d_in[1];
    const float* n = (const float*)d_in[2];
    const float* m = (const float*)d_in[3];
    const float* h = (const float*)d_in[4];
    const float* conv_state = (const float*)d_in[5];
    const float* conv_kernel = (const float*)d_in[6];
    const float* conv_bias = (const float*)d_in[7];
    const float* W[8];
    for (int i = 0; i < 8; ++i) W[i] = (const float*)d_in[8 + i];
    const float* bgi = (const float*)d_in[16];
    const float* bgf = (const float*)d_in[17];
    const float* bgz = (const float*)d_in[18];
    const float* bgo = (const float*)d_in[19];
    const float* ln_scale = (const float*)d_in[20];
    float* out = (float*)d_out;

    char* ws = (char*)d_ws;
    int* flag = (int*)ws;
    u16* convact = (u16*)(ws + 256);
    u16* hbf = convact + BF_ELEMS;
    u16* inbf = hbf + BF_ELEMS;
    u16* wt = inbf + BF_ELEMS;                       // 8*4*65536 bf16
    u16* gates16 = wt + (size_t)8 * 4 * 65536;       // 4 * BF_ELEMS bf16

    hipMemsetAsync(flag, 0, 4, stream);
    kprep<<<6144, 256, 0, stream>>>(inputs, conv_state, conv_kernel, conv_bias, h, n,
                                    W[0], W[1], W[2], W[3], W[4], W[5], W[6], W[7],
                                    out + 5 * (size_t)BF_ELEMS, convact, hbf, inbf, wt, flag);
    kgemm<<<dim3(32, 32), 256, 0, stream>>>(convact, inbf, hbf, wt,
                                            bgi, bgf, bgz, bgo, gates16);
    kpoint<<<4096, 256, 0, stream>>>(gates16, c, n, m, ln_scale, flag, out);
}